// Round 1
// baseline (978.568 us; speedup 1.0000x reference)
//
#include <hip/hip_runtime.h>
#include <cstdint>
#include <cstddef>

#define H_ 64
#define W_ 64
#define T_ 32
#define CIN_ 16
#define COUT_ 64
#define K_ 432   // 16*3*3*3

// ---------------- prep: Gram matrix d[64][64] (fp64 accumulate) ----------------
__global__ void prep_d(const float* __restrict__ w, float* __restrict__ d_f32,
                       double* __restrict__ norm_d) {
    const int i = blockIdx.x;   // 0..63
    const int j = threadIdx.x;  // 0..63
    const float* wi = w + i * K_;
    const float* wj = w + j * K_;
    double acc = 0.0;
    for (int k = 0; k < K_; ++k) acc += (double)wi[k] * (double)wj[k];
    d_f32[i * 64 + j] = (float)acc;
    if (i == j) norm_d[i] = acc;
}

// ---------------- fused conv3d + spiking recurrence ----------------
__launch_bounds__(512, 1)
__global__ void fused_snn(const float* __restrict__ xg, const float* __restrict__ wg,
                          const float* __restrict__ beta_g, const float* __restrict__ bias_g,
                          const float* __restrict__ d_f32, const double* __restrict__ norm_d,
                          float* __restrict__ out) {
    __shared__ __align__(16) float w_lds[K_ * 64];        // [k][cout]  110592 B
    __shared__ __align__(16) float d_lds[64 * 64];        // [b][c]     16384 B
    __shared__ __align__(16) float x_win[3 * CIN_ * 100]; // [slot][cin][10][10] 19200 B
    __shared__ unsigned int masks[2][64][2];              // dbuf spike bitmask  1024 B

    const int tid = threadIdx.x;
    const int b   = blockIdx.x;      // 0..3
    const int ty0 = blockIdx.y * 8;
    const int tx0 = blockIdx.z * 8;

    // --- one-time LDS staging ---
    for (int i = tid; i < K_ * 64; i += 512) {       // w transposed -> [k][c]
        int c = i / K_;
        int k = i - c * K_;
        w_lds[k * 64 + c] = wg[i];
    }
    for (int i = tid; i < 4096; i += 512) d_lds[i] = d_f32[i];
    if (tid < 128) masks[1][tid >> 1][tid & 1] = 0;  // rbuf for t=0

    // preload x slice z=0 into slot 0
    for (int i = tid; i < CIN_ * 100; i += 512) {
        int cin = i / 100; int r = i - cin * 100; int yy = r / 10; int xx = r - yy * 10;
        int gy = ty0 - 1 + yy, gx = tx0 - 1 + xx;
        float v = 0.f;
        if (gy >= 0 && gy < H_ && gx >= 0 && gx < W_)
            v = xg[((size_t)(b * CIN_ + 0 + cin) * T_ + 0) * (H_ * W_) + gy * W_ + gx];
        x_win[(0 * CIN_ + cin) * 100 + yy * 10 + xx] = v;
    }

    // --- per-thread mapping: 4 couts x 2 pixels ---
    const int cgrp = tid >> 5;        // 0..15
    const int pg   = tid & 31;        // 0..31
    const int c0   = cgrp * 4;
    const int p0   = pg * 2;
    const int y0   = p0 >> 3;         // 0..7
    const int x0   = p0 & 7;          // 0,2,4,6
    const int gy   = ty0 + y0, gx = tx0 + x0;

    const double beta = (double)beta_g[0];
    const double omb  = 1.0 - beta;
    double inv[4], bbias[4];
#pragma unroll
    for (int ci = 0; ci < 4; ++ci) {
        inv[ci]   = 1.0 / (norm_d[c0 + ci] + 1e-8);
        bbias[ci] = (double)bias_g[c0 + ci];
    }
    double mem[4][2] = {};

    for (int t = 0; t < T_; ++t) {
        __syncthreads();  // barA: prev conv reads + mask sets complete

        if (tid < 128) masks[t & 1][tid >> 1][tid & 1] = 0;  // clear wbuf

        if (t + 1 < T_) {  // load slice z=t+1 into slot (t+1)%3
            const int z = t + 1; const int slot = z % 3;
            for (int i = tid; i < CIN_ * 100; i += 512) {
                int cin = i / 100; int r = i - cin * 100; int yy = r / 10; int xx = r - yy * 10;
                int gyy = ty0 - 1 + yy, gxx = tx0 - 1 + xx;
                float v = 0.f;
                if (gyy >= 0 && gyy < H_ && gxx >= 0 && gxx < W_)
                    v = xg[((size_t)(b * CIN_ + cin) * T_ + z) * (H_ * W_) + gyy * W_ + gxx];
                x_win[(slot * CIN_ + cin) * 100 + yy * 10 + xx] = v;
            }
        }
        __syncthreads();  // barB: window + masks ready

        // ---- conv: fp64 accumulate, K=432 ----
        double acc[4][2] = {};
        int slots[3]; bool zok[3];
#pragma unroll
        for (int dz = 0; dz < 3; ++dz) {
            int z = t - 1 + dz;
            zok[dz] = (z >= 0 && z < T_);
            slots[dz] = zok[dz] ? (z % 3) : 0;
        }
        for (int cin = 0; cin < CIN_; ++cin) {
#pragma unroll
            for (int dz = 0; dz < 3; ++dz) {
                if (!zok[dz]) continue;   // zero-padding contributes nothing
                const float* xs = &x_win[(slots[dz] * CIN_ + cin) * 100];
#pragma unroll
                for (int dy = 0; dy < 3; ++dy) {
                    const float* xr = xs + (y0 + dy) * 10 + x0;
#pragma unroll
                    for (int dx = 0; dx < 3; ++dx) {
                        const double xv0 = (double)xr[dx];
                        const double xv1 = (double)xr[dx + 1];
                        const int k = cin * 27 + dz * 9 + dy * 3 + dx;
                        const float4 wv = *reinterpret_cast<const float4*>(&w_lds[k * 64 + c0]);
                        acc[0][0] += (double)wv.x * xv0; acc[0][1] += (double)wv.x * xv1;
                        acc[1][0] += (double)wv.y * xv0; acc[1][1] += (double)wv.y * xv1;
                        acc[2][0] += (double)wv.z * xv0; acc[2][1] += (double)wv.z * xv1;
                        acc[3][0] += (double)wv.w * xv0; acc[3][1] += (double)wv.w * xv1;
                    }
                }
            }
        }

        // ---- rst from previous spikes (sparse via bitmask) ----
        double rst[4][2] = {};
        const int rb = (t + 1) & 1;
#pragma unroll
        for (int pj = 0; pj < 2; ++pj) {
#pragma unroll
            for (int wrd = 0; wrd < 2; ++wrd) {
                unsigned int m = masks[rb][p0 + pj][wrd];
                while (m) {
                    int bb_ = __ffs(m) - 1; m &= (m - 1);
                    int bch = wrd * 32 + bb_;
#pragma unroll
                    for (int ci = 0; ci < 4; ++ci)
                        rst[ci][pj] += (double)d_lds[bch * 64 + c0 + ci];
                }
            }
        }

        // ---- membrane update, spike, store ----
        unsigned int nib[2] = {0u, 0u};
#pragma unroll
        for (int ci = 0; ci < 4; ++ci) {
            float2 ov;
#pragma unroll
            for (int pj = 0; pj < 2; ++pj) {
                mem[ci][pj] = (mem[ci][pj] - rst[ci][pj]) * beta + acc[ci][pj] * omb;
                double mthr = mem[ci][pj] * inv[ci] - bbias[ci];
                int s = mthr > 0.0;
                float sv = s ? 1.0f : 0.0f;
                if (pj) ov.y = sv; else ov.x = sv;
                nib[pj] |= (unsigned int)s << ci;
            }
            size_t oidx = ((size_t)(b * COUT_ + c0 + ci) * T_ + t) * (size_t)(H_ * W_)
                        + (size_t)gy * W_ + gx;
            *reinterpret_cast<float2*>(&out[oidx]) = ov;
        }
        const int wrd = cgrp >> 3;
        const int sh  = c0 & 31;
#pragma unroll
        for (int pj = 0; pj < 2; ++pj)
            if (nib[pj]) atomicOr(&masks[t & 1][p0 + pj][wrd], nib[pj] << sh);
    }
}

extern "C" void kernel_launch(void* const* d_in, const int* in_sizes, int n_in,
                              void* d_out, int out_size, void* d_ws, size_t ws_size,
                              hipStream_t stream) {
    const float* x    = (const float*)d_in[0];
    const float* w    = (const float*)d_in[1];
    const float* beta = (const float*)d_in[2];
    const float* bias = (const float*)d_in[3];
    float* out = (float*)d_out;

    float*  d_f32  = (float*)d_ws;                       // 64*64 floats
    double* norm_d = (double*)((char*)d_ws + 64 * 64 * 4); // 64 doubles @16KB

    prep_d<<<dim3(64), dim3(64), 0, stream>>>(w, d_f32, norm_d);
    fused_snn<<<dim3(4, 8, 8), dim3(512), 0, stream>>>(x, w, beta, bias, d_f32, norm_d, out);
}

// Round 2
// 562.270 us; speedup vs baseline: 1.7404x; 1.7404x over previous
//
#include <hip/hip_runtime.h>
#include <cstdint>
#include <cstddef>

#define H_ 64
#define W_ 64
#define T_ 32
#define CIN_ 16
#define COUT_ 64
#define K_ 432
#define TH_ 4
#define TW_ 16
#define WR_ 6
#define WC_ 18
#define WSZ_ (WR_ * WC_)     // 108
#define XTOT_ (CIN_ * WSZ_)  // 1728
#define NSLOT_ 4

// ---- prep: w_t[k][cout] f32, Gram d64[64][64] f64, inv64[64] f64 ----
__global__ void prep(const float* __restrict__ w, float* __restrict__ w_t,
                     double* __restrict__ d64, double* __restrict__ inv64) {
    const int i = blockIdx.x;   // cout row
    const int j = threadIdx.x;  // 0..63
    const float* wi = w + i * K_;
    const float* wj = w + j * K_;
    double acc = 0.0;
    for (int k = 0; k < K_; ++k) acc += (double)wi[k] * (double)wj[k];
    d64[i * 64 + j] = acc;
    if (i == j) inv64[i] = 1.0 / (acc + 1e-8);
    for (int k = j; k < K_; k += 64) w_t[k * 64 + i] = wi[k];
}

// ---- fused conv3d + spiking recurrence ----
__launch_bounds__(512, 1)
__global__ void fused_snn(const float* __restrict__ xg,
                          const float* __restrict__ beta_g, const float* __restrict__ bias_g,
                          const float* __restrict__ w_t, const double* __restrict__ d64,
                          const double* __restrict__ inv64, float* __restrict__ out) {
    __shared__ __align__(16) float x_win[NSLOT_ * XTOT_];   // 27648 B
    __shared__ __align__(16) double d_lds[64 * 65];         // 33280 B (padded rows)
    __shared__ unsigned int masks[2][64][2];                // 1024 B

    const int tid = threadIdx.x;
    const int b   = blockIdx.x;          // batch 0..3
    const int ty0 = blockIdx.y * TH_;    // 16 tiles of 4 rows
    const int tx0 = blockIdx.z * TW_;    // 4 tiles of 16 cols

    const int wv   = __builtin_amdgcn_readfirstlane(tid >> 6);  // wave 0..7
    const int lane = tid & 63;
    const int py   = lane >> 4;          // 0..3
    const int px   = lane & 15;          // 0..15
    const int c0   = wv * 8;             // wave owns couts [c0, c0+8)
    const int xoff = py * WC_ + px;

    // d -> LDS (padded to 65 doubles/row to break bank alignment)
    for (int i = tid; i < 4096; i += 512)
        d_lds[(i >> 6) * 65 + (i & 63)] = d64[i];
    if (tid < 128) masks[1][tid >> 1][tid & 1] = 0u;  // rbuf for t=0

    // pre-stage slices z=0,1 into slots 0,1
    for (int z = 0; z < 2; ++z) {
        for (int i = tid; i < XTOT_; i += 512) {
            int cin = i / WSZ_;
            int r2  = i - cin * WSZ_;
            int yy  = r2 / WC_;
            int xx  = r2 - yy * WC_;
            int gy = ty0 - 1 + yy, gx = tx0 - 1 + xx;
            float v = 0.f;
            if (gy >= 0 && gy < H_ && gx >= 0 && gx < W_)
                v = xg[((size_t)(b * CIN_ + cin) * T_ + z) * (H_ * W_) + gy * W_ + gx];
            x_win[(z * CIN_ + cin) * WSZ_ + r2] = v;
        }
    }

    const double beta = (double)beta_g[0];
    const double omb  = 1.0 - beta;
    double inv_[8], bb[8];
#pragma unroll
    for (int ci = 0; ci < 8; ++ci) {
        inv_[ci] = inv64[c0 + ci];
        bb[ci]   = (double)bias_g[c0 + ci];
    }
    double mem[8];
#pragma unroll
    for (int ci = 0; ci < 8; ++ci) mem[ci] = 0.0;

    // precompute prefetch/staging indices (4 elems max per thread)
    int  pf_cin[4], pf_r2[4];
    size_t pf_goff[4];
    bool pf_ok[4], pf_in[4];
#pragma unroll
    for (int r = 0; r < 4; ++r) {
        int i = tid + r * 512;
        pf_ok[r] = (i < XTOT_);
        int cin = i / WSZ_;
        int r2  = i - cin * WSZ_;
        int yy  = r2 / WC_;
        int xx  = r2 - yy * WC_;
        pf_cin[r] = cin; pf_r2[r] = r2;
        int gy = ty0 - 1 + yy, gx = tx0 - 1 + xx;
        pf_in[r]  = pf_ok[r] && gy >= 0 && gy < H_ && gx >= 0 && gx < W_;
        pf_goff[r] = (size_t)(b * CIN_ + cin) * (T_ * H_ * W_) + (size_t)gy * W_ + gx;
    }

    for (int t = 0; t < T_; ++t) {
        __syncthreads();   // A: prev LDS writes + prev mask ORs visible
        if (tid < 128) masks[t & 1][tid >> 1][tid & 1] = 0u;  // clear wbuf

        // issue async prefetch of slice z=t+2 into regs (hidden under conv)
        float R[4];
        const int zp = t + 2;
        if (zp < T_) {
#pragma unroll
            for (int r = 0; r < 4; ++r) {
                R[r] = 0.f;
                if (pf_in[r]) R[r] = xg[pf_goff[r] + (size_t)zp * (H_ * W_)];
            }
        }

        // ---- conv: fp32 products, per-cin fp64 accumulate ----
        double accd[8];
#pragma unroll
        for (int ci = 0; ci < 8; ++ci) accd[ci] = 0.0;

        int slot_[3]; bool zok[3];
#pragma unroll
        for (int dz = 0; dz < 3; ++dz) {
            int z = t - 1 + dz;
            zok[dz]  = (z >= 0 && z < T_);
            slot_[dz] = zok[dz] ? (z & 3) : 0;
        }

        for (int cin = 0; cin < CIN_; ++cin) {
            float cacc[8];
#pragma unroll
            for (int ci = 0; ci < 8; ++ci) cacc[ci] = 0.f;
#pragma unroll
            for (int dz = 0; dz < 3; ++dz) {
                if (!zok[dz]) continue;
                const float* xs = &x_win[(slot_[dz] * CIN_ + cin) * WSZ_] + xoff;
                const float* wr = w_t + (cin * 27 + dz * 9) * 64 + c0;  // wave-uniform -> s_load
#pragma unroll
                for (int dy = 0; dy < 3; ++dy) {
                    const float xv0 = xs[dy * WC_ + 0];
                    const float xv1 = xs[dy * WC_ + 1];
                    const float xv2 = xs[dy * WC_ + 2];
                    const float* wk = wr + dy * 192;
#pragma unroll
                    for (int ci = 0; ci < 8; ++ci) cacc[ci] = fmaf(wk[ci],       xv0, cacc[ci]);
#pragma unroll
                    for (int ci = 0; ci < 8; ++ci) cacc[ci] = fmaf(wk[64 + ci],  xv1, cacc[ci]);
#pragma unroll
                    for (int ci = 0; ci < 8; ++ci) cacc[ci] = fmaf(wk[128 + ci], xv2, cacc[ci]);
                }
            }
#pragma unroll
            for (int ci = 0; ci < 8; ++ci) accd[ci] += (double)cacc[ci];
        }

        // ---- rst from previous spikes (sparse via bitmask), fp64 d ----
        double rstv[8];
#pragma unroll
        for (int ci = 0; ci < 8; ++ci) rstv[ci] = 0.0;
        const int rb = (t + 1) & 1;
#pragma unroll
        for (int wrd = 0; wrd < 2; ++wrd) {
            unsigned int m = masks[rb][lane][wrd];
            while (m) {
                int bit = __ffs(m) - 1;
                m &= m - 1;
                const double* drow = &d_lds[(wrd * 32 + bit) * 65 + c0];
#pragma unroll
                for (int ci = 0; ci < 8; ++ci) rstv[ci] += drow[ci];
            }
        }

        // ---- membrane update, spike, store ----
        unsigned int nib = 0u;
        const size_t obase = ((size_t)(b * COUT_ + c0) * T_ + t) * (size_t)(H_ * W_)
                           + (size_t)(ty0 + py) * W_ + (tx0 + px);
#pragma unroll
        for (int ci = 0; ci < 8; ++ci) {
            mem[ci] = (mem[ci] - rstv[ci]) * beta + accd[ci] * omb;
            const double mthr = mem[ci] * inv_[ci] - bb[ci];
            const int s = mthr > 0.0 ? 1 : 0;
            out[obase + (size_t)ci * (T_ * H_ * W_)] = (float)s;
            nib |= (unsigned int)s << ci;
        }

        __syncthreads();   // B: all clears done before ORs; all conv reads done
        if (nib) atomicOr(&masks[t & 1][lane][wv >> 2], nib << ((wv & 3) * 8));

        // write prefetched slice into its LDS slot (vmcnt drain overlapped with conv)
        if (zp < T_) {
            const int slot = zp & 3;
#pragma unroll
            for (int r = 0; r < 4; ++r)
                if (pf_ok[r])
                    x_win[(slot * CIN_ + pf_cin[r]) * WSZ_ + pf_r2[r]] = R[r];
        }
    }
}

extern "C" void kernel_launch(void* const* d_in, const int* in_sizes, int n_in,
                              void* d_out, int out_size, void* d_ws, size_t ws_size,
                              hipStream_t stream) {
    const float* x    = (const float*)d_in[0];
    const float* w    = (const float*)d_in[1];
    const float* beta = (const float*)d_in[2];
    const float* bias = (const float*)d_in[3];
    float* out = (float*)d_out;

    float*  w_t   = (float*)d_ws;                                   // 110592 B
    double* d64   = (double*)((char*)d_ws + 110592);                // 32768 B
    double* inv64 = (double*)((char*)d_ws + 110592 + 32768);        // 512 B

    prep<<<dim3(64), dim3(64), 0, stream>>>(w, w_t, d64, inv64);
    fused_snn<<<dim3(4, 16, 4), dim3(512), 0, stream>>>(x, beta, bias, w_t, d64, inv64, out);
}

// Round 3
// 522.067 us; speedup vs baseline: 1.8744x; 1.0770x over previous
//
#include <hip/hip_runtime.h>
#include <cstdint>
#include <cstddef>

#define H_ 64
#define W_ 64
#define T_ 32
#define CIN_ 16
#define COUT_ 64
#define K_ 432
#define TH_ 4
#define TW_ 16
#define WR_ 6
#define WC_ 18
#define WSZ_ (WR_ * WC_)     // 108
#define XTOT_ (CIN_ * WSZ_)  // 1728
#define NSLOT_ 4
#define NTHR_ 1024

// ---- prep: w_t[k][cout] f32, Gram d64[64][64] f64, inv64[64] f64 ----
__global__ void prep(const float* __restrict__ w, float* __restrict__ w_t,
                     double* __restrict__ d64, double* __restrict__ inv64) {
    const int i = blockIdx.x;   // cout row
    const int j = threadIdx.x;  // 0..63
    const float* wi = w + i * K_;
    const float* wj = w + j * K_;
    double acc = 0.0;
    for (int k = 0; k < K_; ++k) acc += (double)wi[k] * (double)wj[k];
    d64[i * 64 + j] = acc;
    if (i == j) inv64[i] = 1.0 / (acc + 1e-8);
    for (int k = j; k < K_; k += 64) w_t[k * 64 + i] = wi[k];
}

// ---- fused conv3d + spiking recurrence ----
__launch_bounds__(NTHR_, 1)
__global__ void fused_snn(const float* __restrict__ xg,
                          const float* __restrict__ beta_g, const float* __restrict__ bias_g,
                          const float* __restrict__ w_t, const double* __restrict__ d64,
                          const double* __restrict__ inv64, float* __restrict__ out) {
    __shared__ __align__(16) float x_win[NSLOT_ * XTOT_];   // 27648 B
    __shared__ __align__(16) double d_lds[64 * 65];         // 33280 B (padded rows)
    __shared__ unsigned int masks[2][64][2];                // 1024 B

    const int tid = threadIdx.x;
    const int b   = blockIdx.x;          // batch 0..3
    const int ty0 = blockIdx.y * TH_;    // 16 tiles of 4 rows
    const int tx0 = blockIdx.z * TW_;    // 4 tiles of 16 cols

    const int wv   = __builtin_amdgcn_readfirstlane(tid >> 6);  // wave 0..15
    const int lane = tid & 63;
    const int py   = lane >> 4;          // 0..3
    const int px   = lane & 15;          // 0..15
    const int c0   = wv * 4;             // wave owns couts [c0, c0+4)
    const int xoff = py * WC_ + px;

    // d -> LDS (padded to 65 doubles/row to break bank alignment)
    for (int i = tid; i < 4096; i += NTHR_)
        d_lds[(i >> 6) * 65 + (i & 63)] = d64[i];
    if (tid < 128) masks[1][tid >> 1][tid & 1] = 0u;  // rbuf for t=0

    // pre-stage slices z=0,1 into slots 0,1
    for (int z = 0; z < 2; ++z) {
        for (int i = tid; i < XTOT_; i += NTHR_) {
            int cin = i / WSZ_;
            int r2  = i - cin * WSZ_;
            int yy  = r2 / WC_;
            int xx  = r2 - yy * WC_;
            int gy = ty0 - 1 + yy, gx = tx0 - 1 + xx;
            float v = 0.f;
            if (gy >= 0 && gy < H_ && gx >= 0 && gx < W_)
                v = xg[((size_t)(b * CIN_ + cin) * T_ + z) * (H_ * W_) + gy * W_ + gx];
            x_win[(z * CIN_ + cin) * WSZ_ + r2] = v;
        }
    }

    const double beta = (double)beta_g[0];
    const double omb  = 1.0 - beta;
    double inv_[4], bb[4];
#pragma unroll
    for (int ci = 0; ci < 4; ++ci) {
        inv_[ci] = inv64[c0 + ci];
        bb[ci]   = (double)bias_g[c0 + ci];
    }
    double mem[4];
#pragma unroll
    for (int ci = 0; ci < 4; ++ci) mem[ci] = 0.0;

    // precompute prefetch/staging indices (2 elems max per thread)
    int  pf_cin[2], pf_r2[2];
    size_t pf_goff[2];
    bool pf_ok[2], pf_in[2];
#pragma unroll
    for (int r = 0; r < 2; ++r) {
        int i = tid + r * NTHR_;
        pf_ok[r] = (i < XTOT_);
        int cin = i / WSZ_;
        int r2  = i - cin * WSZ_;
        int yy  = r2 / WC_;
        int xx  = r2 - yy * WC_;
        pf_cin[r] = cin; pf_r2[r] = r2;
        int gy = ty0 - 1 + yy, gx = tx0 - 1 + xx;
        pf_in[r]  = pf_ok[r] && gy >= 0 && gy < H_ && gx >= 0 && gx < W_;
        pf_goff[r] = (size_t)(b * CIN_ + cin) * (T_ * H_ * W_) + (size_t)gy * W_ + gx;
    }

    for (int t = 0; t < T_; ++t) {
        __syncthreads();   // A: prev LDS writes + prev mask ORs visible
        if (tid < 128) masks[t & 1][tid >> 1][tid & 1] = 0u;  // clear wbuf

        // issue prefetch of slice z=t+2 into regs (hidden under conv)
        float R[2];
        const int zp = t + 2;
        if (zp < T_) {
#pragma unroll
            for (int r = 0; r < 2; ++r) {
                R[r] = 0.f;
                if (pf_in[r]) R[r] = xg[pf_goff[r] + (size_t)zp * (H_ * W_)];
            }
        }

        // ---- conv: fp32 products, per-cin fp64 accumulate ----
        double accd[4];
#pragma unroll
        for (int ci = 0; ci < 4; ++ci) accd[ci] = 0.0;

        int slot_[3]; bool zok[3];
#pragma unroll
        for (int dz = 0; dz < 3; ++dz) {
            int z = t - 1 + dz;
            zok[dz]  = (z >= 0 && z < T_);
            slot_[dz] = zok[dz] ? (z & 3) : 0;
        }

        for (int cin = 0; cin < CIN_; ++cin) {
            float cacc[4];
#pragma unroll
            for (int ci = 0; ci < 4; ++ci) cacc[ci] = 0.f;
#pragma unroll
            for (int dz = 0; dz < 3; ++dz) {
                if (!zok[dz]) continue;
                const float* xs = &x_win[(slot_[dz] * CIN_ + cin) * WSZ_] + xoff;
                const float* wr = w_t + (cin * 27 + dz * 9) * 64 + c0;  // wave-uniform -> s_load
#pragma unroll
                for (int dy = 0; dy < 3; ++dy) {
                    const float xv0 = xs[dy * WC_ + 0];
                    const float xv1 = xs[dy * WC_ + 1];
                    const float xv2 = xs[dy * WC_ + 2];
                    const float4 w0 = *reinterpret_cast<const float4*>(wr + dy * 192);
                    const float4 w1 = *reinterpret_cast<const float4*>(wr + dy * 192 + 64);
                    const float4 w2 = *reinterpret_cast<const float4*>(wr + dy * 192 + 128);
                    cacc[0] = fmaf(w0.x, xv0, cacc[0]);
                    cacc[1] = fmaf(w0.y, xv0, cacc[1]);
                    cacc[2] = fmaf(w0.z, xv0, cacc[2]);
                    cacc[3] = fmaf(w0.w, xv0, cacc[3]);
                    cacc[0] = fmaf(w1.x, xv1, cacc[0]);
                    cacc[1] = fmaf(w1.y, xv1, cacc[1]);
                    cacc[2] = fmaf(w1.z, xv1, cacc[2]);
                    cacc[3] = fmaf(w1.w, xv1, cacc[3]);
                    cacc[0] = fmaf(w2.x, xv2, cacc[0]);
                    cacc[1] = fmaf(w2.y, xv2, cacc[1]);
                    cacc[2] = fmaf(w2.z, xv2, cacc[2]);
                    cacc[3] = fmaf(w2.w, xv2, cacc[3]);
                }
            }
#pragma unroll
            for (int ci = 0; ci < 4; ++ci) accd[ci] += (double)cacc[ci];
        }

        // ---- rst from previous spikes (sparse via bitmask), fp64 d ----
        double rstv[4];
#pragma unroll
        for (int ci = 0; ci < 4; ++ci) rstv[ci] = 0.0;
        const int rb = (t + 1) & 1;
#pragma unroll
        for (int wrd = 0; wrd < 2; ++wrd) {
            unsigned int m = masks[rb][lane][wrd];
            while (m) {
                int bit = __ffs(m) - 1;
                m &= m - 1;
                const double* drow = &d_lds[(wrd * 32 + bit) * 65 + c0];
#pragma unroll
                for (int ci = 0; ci < 4; ++ci) rstv[ci] += drow[ci];
            }
        }

        // ---- membrane update, spike, store ----
        unsigned int nib = 0u;
        const size_t obase = ((size_t)(b * COUT_ + c0) * T_ + t) * (size_t)(H_ * W_)
                           + (size_t)(ty0 + py) * W_ + (tx0 + px);
#pragma unroll
        for (int ci = 0; ci < 4; ++ci) {
            mem[ci] = (mem[ci] - rstv[ci]) * beta + accd[ci] * omb;
            const double mthr = mem[ci] * inv_[ci] - bb[ci];
            const int s = mthr > 0.0 ? 1 : 0;
            out[obase + (size_t)ci * (T_ * H_ * W_)] = (float)s;
            nib |= (unsigned int)s << ci;
        }

        __syncthreads();   // B: all clears + conv reads done before ORs / x writes
        if (nib) atomicOr(&masks[t & 1][lane][wv >> 3], nib << ((wv & 7) * 4));

        // write prefetched slice into its LDS slot
        if (zp < T_) {
            const int slot = zp & 3;
#pragma unroll
            for (int r = 0; r < 2; ++r)
                if (pf_ok[r])
                    x_win[(slot * CIN_ + pf_cin[r]) * WSZ_ + pf_r2[r]] = R[r];
        }
    }
}

extern "C" void kernel_launch(void* const* d_in, const int* in_sizes, int n_in,
                              void* d_out, int out_size, void* d_ws, size_t ws_size,
                              hipStream_t stream) {
    const float* x    = (const float*)d_in[0];
    const float* w    = (const float*)d_in[1];
    const float* beta = (const float*)d_in[2];
    const float* bias = (const float*)d_in[3];
    float* out = (float*)d_out;

    float*  w_t   = (float*)d_ws;                                   // 110592 B
    double* d64   = (double*)((char*)d_ws + 110592);                // 32768 B
    double* inv64 = (double*)((char*)d_ws + 110592 + 32768);        // 512 B

    prep<<<dim3(64), dim3(64), 0, stream>>>(w, w_t, d64, inv64);
    fused_snn<<<dim3(4, 16, 4), dim3(NTHR_), 0, stream>>>(x, beta, bias, w_t, d64, inv64, out);
}